// Round 10
// baseline (157.174 us; speedup 1.0000x reference)
//
#include <hip/hip_runtime.h>
#include <stdint.h>

// Match numpy f32 elementwise semantics: no implicit FMA contraction.
#pragma clang fp contract(off)

#define GRIDN 256
#define NC (GRIDN * GRIDN)
#define RESN 512
#define RBLOCKS 256
#define CAP 1024      // per-cell sort capacity; CAP=2048 regressed 80us (r7: tail-bound)
#define CPB 16        // cells per cellsort block (r9: 2 blocks/cell doubled dispatch
                      // breadth + staging for zero critical-path win — breadth-bound)
#define NB 64         // tri chunks
#define NS 16         // cell-space slices (4096 cells = 16 grid rows = 8KB LDS)
#define SBINS 2048    // packed u32 bins per slice

typedef unsigned short bfraw;
typedef unsigned short u16;

__device__ __forceinline__ float bf2f(bfraw h) {
    return __uint_as_float(((uint32_t)h) << 16);   // bf16 upcast is exact
}
__device__ __forceinline__ bfraw f2bf(float f) {
    uint32_t b = __float_as_uint(f);               // RNE f32 -> bf16
    return (bfraw)((b + 0x7FFFu + ((b >> 16) & 1u)) >> 16);
}
__device__ __forceinline__ uint32_t fkey(float f) {
    uint32_t b = __float_as_uint(f);
    return (b & 0x80000000u) ? ~b : (b | 0x80000000u);
}

// ---------------- partial reduce (sum fp64, min/max fp32) ----------------
__global__ __launch_bounds__(256) void k_reduce1(const bfraw* __restrict__ u, int nrows,
                                                 double* __restrict__ psum,
                                                 float* __restrict__ pmin,
                                                 float* __restrict__ pmax) {
    __shared__ double ssum[256 * 3];
    __shared__ float smin[256 * 3];
    __shared__ float smax[256 * 3];
    int t = threadIdx.x;
    double s0 = 0.0, s1 = 0.0, s2 = 0.0;
    float mn0 = INFINITY, mn1 = INFINITY, mn2 = INFINITY;
    float mx0 = -INFINITY, mx1 = -INFINITY, mx2 = -INFINITY;
    for (int r = blockIdx.x * 256 + t; r < nrows; r += 256 * RBLOCKS) {
        float a = bf2f(u[3 * r + 0]);
        float b = bf2f(u[3 * r + 1]);
        float c = bf2f(u[3 * r + 2]);
        s0 += (double)a; s1 += (double)b; s2 += (double)c;
        mn0 = fminf(mn0, a); mx0 = fmaxf(mx0, a);
        mn1 = fminf(mn1, b); mx1 = fmaxf(mx1, b);
        mn2 = fminf(mn2, c); mx2 = fmaxf(mx2, c);
    }
    ssum[t * 3 + 0] = s0; ssum[t * 3 + 1] = s1; ssum[t * 3 + 2] = s2;
    smin[t * 3 + 0] = mn0; smin[t * 3 + 1] = mn1; smin[t * 3 + 2] = mn2;
    smax[t * 3 + 0] = mx0; smax[t * 3 + 1] = mx1; smax[t * 3 + 2] = mx2;
    __syncthreads();
    for (int st = 128; st > 0; st >>= 1) {
        if (t < st) {
            for (int c = 0; c < 3; c++) {
                ssum[t * 3 + c] += ssum[(t + st) * 3 + c];
                smin[t * 3 + c] = fminf(smin[t * 3 + c], smin[(t + st) * 3 + c]);
                smax[t * 3 + c] = fmaxf(smax[t * 3 + c], smax[(t + st) * 3 + c]);
            }
        }
        __syncthreads();
    }
    if (t == 0) {
        for (int c = 0; c < 3; c++) {
            psum[blockIdx.x * 3 + c] = ssum[c];
            pmin[blockIdx.x * 3 + c] = smin[c];
            pmax[blockIdx.x * 3 + c] = smax[c];
        }
    }
}

// ---------------- finalize constants ----------------
__global__ __launch_bounds__(256) void k_reduce2(const double* __restrict__ psum,
                                                 const float* __restrict__ pmin,
                                                 const float* __restrict__ pmax,
                                                 int nrows, float* __restrict__ cst) {
    __shared__ double ssum[256 * 3];
    __shared__ float smin[256 * 3];
    __shared__ float smax[256 * 3];
    int t = threadIdx.x;
    for (int c = 0; c < 3; c++) {
        ssum[t * 3 + c] = psum[t * 3 + c];
        smin[t * 3 + c] = pmin[t * 3 + c];
        smax[t * 3 + c] = pmax[t * 3 + c];
    }
    __syncthreads();
    for (int st = 128; st > 0; st >>= 1) {
        if (t < st) {
            for (int c = 0; c < 3; c++) {
                ssum[t * 3 + c] += ssum[(t + st) * 3 + c];
                smin[t * 3 + c] = fminf(smin[t * 3 + c], smin[(t + st) * 3 + c]);
                smax[t * 3 + c] = fmaxf(smax[t * 3 + c], smax[(t + st) * 3 + c]);
            }
        }
        __syncthreads();
    }
    if (t == 0) {
        float fn = (float)nrows;
        float m0 = (float)ssum[0] / fn;
        float m1 = (float)ssum[1] / fn;
        float m2 = (float)ssum[2] / fn;
        // fp32 rounding is monotone: max_r(u - mean) == colmax - mean exactly.
        float vmax = fmaxf(fmaxf(smax[0] - m0, smax[1] - m1), smax[2] - m2);
        float vmin = fminf(fminf(smin[0] - m0, smin[1] - m1), smin[2] - m2);
        float span = fmaxf(vmax - vmin, 1e-06f);
        float s = 0.5f / span;   // SCALE / span
        cst[0] = m0; cst[1] = m1; cst[2] = m2; cst[3] = s;
    }
}

// ---------------- per-triangle setup (pure streaming, NO atomics) ----------------
// tcs layout per tri (8 floats): cpx0,cpy0,cpx1,cpy1,cpx2,cpy2,shade,0
// tbox: lox | loy<<8 | hx<<16 | hy<<24  with hx=min(hix,lox+3), hy=min(hiy,loy+3)
__global__ __launch_bounds__(256) void k_setup(const bfraw* __restrict__ u,
                                               const int* __restrict__ faces,
                                               const bfraw* __restrict__ mvp,
                                               const bfraw* __restrict__ light,
                                               const float* __restrict__ cst,
                                               int F,
                                               float* __restrict__ tcs,
                                               uint32_t* __restrict__ tz,
                                               uint32_t* __restrict__ tbox) {
    int f = blockIdx.x * 256 + threadIdx.x;
    if (f >= F) return;
    float m0 = cst[0], m1 = cst[1], m2 = cst[2], s = cst[3];
    float M[12];
    for (int i = 0; i < 12; i++) M[i] = bf2f(mvp[i]);

    float vx[3], vy[3], vz[3], cpx[3], cpy[3], zc[3];
    for (int j = 0; j < 3; j++) {
        int idx = faces[3 * f + j];
        float a = bf2f(u[3 * idx + 0]);
        float b = bf2f(u[3 * idx + 1]);
        float c = bf2f(u[3 * idx + 2]);
        float x = (a - m0) * s;
        float y = (b - m1) * s;
        float z = (c - m2) * s;
        vx[j] = x; vy[j] = y; vz[j] = z;
        // BLAS-style ascending-k fma chain; w=1 -> plain add of M[row][3]
        float cx = fmaf(x, M[0], 0.0f);
        cx = fmaf(y, M[1], cx); cx = fmaf(z, M[2], cx); cx = cx + M[3];
        float cy = fmaf(x, M[4], 0.0f);
        cy = fmaf(y, M[5], cy); cy = fmaf(z, M[6], cy); cy = cy + M[7];
        float cz = fmaf(x, M[8], 0.0f);
        cz = fmaf(y, M[9], cz); cz = fmaf(z, M[10], cz); cz = cz + M[11];
        cpx[j] = (cx + 1.0f) * 0.5f;
        cpy[j] = (cy + 1.0f) * 0.5f;
        zc[j] = cz;
    }
    float zmean = ((zc[0] + zc[1]) + zc[2]) / 3.0f;

    float e1x = vx[0] - vx[1], e1y = vy[0] - vy[1], e1z = vz[0] - vz[1];
    float e2x = vx[2] - vx[1], e2y = vy[2] - vy[1], e2z = vz[2] - vz[1];
    float nx = e1y * e2z - e1z * e2y;
    float ny = e1z * e2x - e1x * e2z;
    float nz = e1x * e2y - e1y * e2x;
    float nn = nx * nx;
    nn = nn + ny * ny;
    nn = nn + nz * nz;
    float d = sqrtf(nn) + 1e-10f;
    float inx = nx / d, iny = ny / d, inz = nz / d;

    float l0 = bf2f(light[0]), l1 = bf2f(light[1]), l2 = bf2f(light[2]);
    float p0 = (-l0) * inx;
    float p1 = (-l1) * iny;
    float p2 = (-l2) * inz;
    float shading = fmaxf((p0 + p1) + p2, 0.0f);

    tcs[f * 8 + 0] = cpx[0]; tcs[f * 8 + 1] = cpy[0];
    tcs[f * 8 + 2] = cpx[1]; tcs[f * 8 + 3] = cpy[1];
    tcs[f * 8 + 4] = cpx[2]; tcs[f * 8 + 5] = cpy[2];
    tcs[f * 8 + 6] = shading;
    tcs[f * 8 + 7] = 0.0f;

    tz[f] = fkey(zmean);

    float mnx = fminf(fminf(cpx[0], cpx[1]), cpx[2]);
    float mny = fminf(fminf(cpy[0], cpy[1]), cpy[2]);
    float mxx = fmaxf(fmaxf(cpx[0], cpx[1]), cpx[2]);
    float mxy = fmaxf(fmaxf(cpy[0], cpy[1]), cpy[2]);
    int lox = (int)floorf(mnx * 256.0f); lox = lox < 0 ? 0 : (lox > 255 ? 255 : lox);
    int loy = (int)floorf(mny * 256.0f); loy = loy < 0 ? 0 : (loy > 255 ? 255 : loy);
    int hix = (int)floorf(mxx * 256.0f); hix = hix < 0 ? 0 : (hix > 255 ? 255 : hix);
    int hiy = (int)floorf(mxy * 256.0f); hiy = hiy < 0 ? 0 : (hiy > 255 ? 255 : hiy);
    int hx = hix < lox + 3 ? hix : lox + 3;   // SPAN=4 window
    int hy = hiy < loy + 3 ? hiy : loy + 3;
    tbox[f] = (uint32_t)lox | ((uint32_t)loy << 8) | ((uint32_t)hx << 16) | ((uint32_t)hy << 24);
}

// ---------------- slice-parallel LDS histogram ----------------
// Slice sl owns grid rows [16*sl, 16*sl+16) (cell>>12 == yy>>4 exactly), so the
// y-loop is clamped instead of per-cell filtered.
__global__ __launch_bounds__(256) void k_count(const uint32_t* __restrict__ tbox,
                                               int F,
                                               u16* __restrict__ blockHist) {
    __shared__ uint32_t hist[SBINS];
    int b = blockIdx.x >> 4;          // chunk
    int sl = blockIdx.x & (NS - 1);   // slice
    int chunk = (F + NB - 1) / NB;
    int fs = b * chunk;
    int fe = fs + chunk < F ? fs + chunk : F;
    int y0 = sl * 16, y1 = y0 + 15;
    for (int i = threadIdx.x; i < SBINS; i += 256) hist[i] = 0u;
    __syncthreads();
    for (int f = fs + threadIdx.x; f < fe; f += 256) {
        uint32_t bx = tbox[f];
        int lox = bx & 255, loy = (bx >> 8) & 255;
        int hx = (bx >> 16) & 255, hy = bx >> 24;
        int ys = loy > y0 ? loy : y0;
        int ye = hy < y1 ? hy : y1;
        for (int yy = ys; yy <= ye; yy++) {
            for (int xx = lox; xx <= hx; xx++) {
                uint32_t c = (uint32_t)(yy * GRIDN + xx) & 4095u;
                atomicAdd(&hist[c >> 1], 1u << (16u * (c & 1u)));
            }
        }
    }
    __syncthreads();
    uint32_t* dst = (uint32_t*)(blockHist + (size_t)b * NC) + sl * SBINS;
    for (int i = threadIdx.x; i < SBINS; i += 256) dst[i] = hist[i];
}

// ---------------- fused: per-cell block-prefix + block-local scan ----------------
__global__ __launch_bounds__(1024) void k_scanA1(u16* __restrict__ blockHist,
                                                 uint32_t* __restrict__ cellOff,
                                                 uint32_t* __restrict__ blockSum) {
    __shared__ uint32_t sc[1024];
    int B = blockIdx.x, t = threadIdx.x;
    int c = B * 1024 + t;
    uint32_t tot = 0;
    for (int b = 0; b < NB; b++) {
        size_t o = (size_t)b * NC + c;
        uint32_t v = blockHist[o];
        blockHist[o] = (u16)tot;              // per-(chunk,cell) base
        tot += v;
    }
    sc[t] = tot;
    __syncthreads();
    for (int st = 1; st < 1024; st <<= 1) {
        uint32_t a = 0;
        if (t >= st) a = sc[t - st];
        __syncthreads();
        if (t >= st) sc[t] += a;
        __syncthreads();
    }
    cellOff[c] = sc[t] - tot;   // exclusive within block
    if (t == 1023) blockSum[B] = sc[1023];
}

// ---------------- fused: block-base add (each block prefixes the 64 sums) -------
__global__ __launch_bounds__(1024) void k_scanB(uint32_t* __restrict__ cellOff,
                                                const uint32_t* __restrict__ blockSum) {
    __shared__ uint32_t pre[65];
    int B = blockIdx.x, t = threadIdx.x;
    if (t == 0) {
        uint32_t run = 0;
        for (int i = 0; i < 64; i++) { pre[i] = run; run += blockSum[i]; }
        pre[64] = run;   // grand total
    }
    __syncthreads();
    cellOff[B * 1024 + t] += pre[B];
    if (B == 63 && t == 1023) cellOff[NC] = pre[64];
}

// ---------------- slice-parallel place: LDS cursor = rank within (chunk,cell) -----
__global__ __launch_bounds__(256) void k_place(const uint32_t* __restrict__ tbox,
                                               const u16* __restrict__ blockHist,
                                               const uint32_t* __restrict__ cellOff,
                                               uint32_t* __restrict__ pairs,
                                               int F) {
    __shared__ uint32_t hist[SBINS];
    int b = blockIdx.x >> 4;
    int sl = blockIdx.x & (NS - 1);
    int chunk = (F + NB - 1) / NB;
    int fs = b * chunk;
    int fe = fs + chunk < F ? fs + chunk : F;
    int y0 = sl * 16, y1 = y0 + 15;
    uint32_t pcap = (uint32_t)F * 16u;
    for (int i = threadIdx.x; i < SBINS; i += 256) hist[i] = 0u;
    __syncthreads();
    for (int f = fs + threadIdx.x; f < fe; f += 256) {
        uint32_t bx = tbox[f];
        int lox = bx & 255, loy = (bx >> 8) & 255;
        int hx = (bx >> 16) & 255, hy = bx >> 24;
        int ys = loy > y0 ? loy : y0;
        int ye = hy < y1 ? hy : y1;
        for (int yy = ys; yy <= ye; yy++) {
            for (int xx = lox; xx <= hx; xx++) {
                uint32_t cell = (uint32_t)(yy * GRIDN + xx);
                uint32_t c = cell & 4095u;
                uint32_t sh = 16u * (c & 1u);
                uint32_t old = atomicAdd(&hist[c >> 1], 1u << sh);
                uint32_t r = (old >> sh) & 0xFFFFu;
                uint32_t pos = cellOff[cell] + (uint32_t)blockHist[(size_t)b * NC + cell] + r;
                if (pos < pcap) pairs[pos] = (uint32_t)f;   // defensive vs poisoned replay
            }
        }
    }
}

// ---------------- per-cell sort by (z,idx) key; keep first 64 sorted ----------------
// CPB cells per 256-thread block (grid-stride): empty/small cells cost a
// block-uniform s_load pair inside a running block instead of a fresh
// workgroup dispatch (r9's 131k-workgroup breadth was the hidden cost).
// Per-cell algorithm unchanged from r8: <=4 keys/thread in fixed register
// slots; rank loop = 1 LDS broadcast + 4 reg compares per j.
__global__ __launch_bounds__(256) void k_cellsort(const uint32_t* __restrict__ cellOff,
                                                  const uint32_t* __restrict__ tz,
                                                  uint32_t* __restrict__ pairs,
                                                  int F) {
    __shared__ uint64_t lkeys[CAP];
    uint32_t pcap = (uint32_t)F * 16u;
    int t = threadIdx.x;
    int cell0 = blockIdx.x * CPB;
    for (int ci = 0; ci < CPB; ci++) {
        int cell = cell0 + ci;
        uint32_t off = cellOff[cell];       // block-uniform -> s_load
        uint32_t end = cellOff[cell + 1];
        if (off > pcap || end > pcap || end < off) continue;   // defensive (uniform)
        uint32_t n = end - off;
        if (n < 2u) continue;               // uniform: no barrier divergence
        uint32_t m = n > CAP ? CAP : n;
        for (uint32_t i = t; i < m; i += 256) {
            uint32_t id = pairs[off + i];
            if (id >= (uint32_t)F) id = 0;   // defensive
            lkeys[i] = ((uint64_t)tz[id] << 32) | id;
        }
        __syncthreads();
        uint64_t k0 = ~0ull, k1 = ~0ull, k2 = ~0ull, k3 = ~0ull;
        uint32_t i0 = t, i1 = t + 256, i2 = t + 512, i3 = t + 768;
        if (i0 < m) k0 = lkeys[i0];
        if (i1 < m) k1 = lkeys[i1];
        if (i2 < m) k2 = lkeys[i2];
        if (i3 < m) k3 = lkeys[i3];
        uint32_t r0 = 0, r1 = 0, r2 = 0, r3 = 0;
        for (uint32_t j = 0; j < m; j++) {
            uint64_t kj = lkeys[j];   // broadcast (all lanes same addr: conflict-free)
            r0 += (kj < k0) ? 1u : 0u;
            r1 += (kj < k1) ? 1u : 0u;
            r2 += (kj < k2) ? 1u : 0u;
            r3 += (kj < k3) ? 1u : 0u;
        }
        if (i0 < m && r0 < 64u) pairs[off + r0] = (uint32_t)(k0 & 0xFFFFFFFFu);
        if (i1 < m && r1 < 64u) pairs[off + r1] = (uint32_t)(k1 & 0xFFFFFFFFu);
        if (i2 < m && r2 < 64u) pairs[off + r2] = (uint32_t)(k2 & 0xFFFFFFFFu);
        if (i3 < m && r3 < 64u) pairs[off + r3] = (uint32_t)(k3 & 0xFFFFFFFFu);
        __syncthreads();   // protect lkeys before next cell's staging (uniform)
    }
}

// ---------------- raster: first inside hit in sorted order ----------------
__global__ __launch_bounds__(256) void k_raster(const float* __restrict__ tcs,
                                                const uint32_t* __restrict__ cellOff,
                                                const uint32_t* __restrict__ pairs,
                                                const bfraw* __restrict__ basec,
                                                const bfraw* __restrict__ bg,
                                                bfraw* __restrict__ out, int F) {
    int p = blockIdx.x * 256 + threadIdx.x;
    int col = p & (RESN - 1);
    int row = p >> 9;
    float px = ((float)col + 0.5f) / 512.0f;
    float py = ((float)row + 0.5f) / 512.0f;
    int cell = (row >> 1) * GRIDN + (col >> 1);
    uint32_t pcap = (uint32_t)F * 16u;
    uint32_t off = cellOff[cell];
    uint32_t end = cellOff[cell + 1];
    uint32_t m = 0;
    if (off <= pcap && end <= pcap && end >= off) {
        uint32_t n = end - off;
        m = n > 64u ? 64u : n;
    }
    float r = bf2f(bg[0]), g = bf2f(bg[1]), b = bf2f(bg[2]);
    for (uint32_t k = 0; k < m; k++) {
        uint32_t id = pairs[off + k];
        if (id >= (uint32_t)F) continue;   // defensive
        const float4 A = *(const float4*)(tcs + (size_t)id * 8);
        const float4 B = *(const float4*)(tcs + (size_t)id * 8 + 4);
        float ax = A.x, ay = A.y, bx = A.z, by = A.w, cx = B.x, cy = B.y;
        float e0 = (bx - ax) * (py - ay) - (by - ay) * (px - ax);
        float e1 = (cx - bx) * (py - by) - (cy - by) * (px - bx);
        float e2 = (ax - cx) * (py - cy) - (ay - cy) * (px - cx);
        bool inside = (e0 >= 0.0f && e1 >= 0.0f && e2 >= 0.0f) ||
                      (e0 <= 0.0f && e1 <= 0.0f && e2 <= 0.0f);
        if (inside) {
            float sh = B.z;
            r = bf2f(basec[3 * id + 0]) * sh;
            g = bf2f(basec[3 * id + 1]) * sh;
            b = bf2f(basec[3 * id + 2]) * sh;
            break;   // sorted order => first hit is the reference's winner
        }
    }
    int o = p * 3;
    out[o + 0] = f2bf(r);
    out[o + 1] = f2bf(g);
    out[o + 2] = f2bf(b);
}

// ---------------- diagnostic: ws too small -> encode ws MB into the image ----------------
__global__ __launch_bounds__(256) void k_diag(bfraw* __restrict__ out, float code) {
    out[blockIdx.x * 256 + threadIdx.x] = f2bf(code);
}

extern "C" void kernel_launch(void* const* d_in, const int* in_sizes, int n_in,
                              void* d_out, int out_size, void* d_ws, size_t ws_size,
                              hipStream_t stream) {
    const bfraw* u = (const bfraw*)d_in[0];
    const bfraw* mvps = (const bfraw*)d_in[1];
    const bfraw* light = (const bfraw*)d_in[2];
    const bfraw* bg = (const bfraw*)d_in[3];
    const bfraw* basec = (const bfraw*)d_in[4];
    const int* faces = (const int*)d_in[5];
    int nrows = in_sizes[0] / 3;
    int F = in_sizes[5] / 3;
    bfraw* out = (bfraw*)d_out;

    char* w = (char*)d_ws;
    size_t off = 0;
    auto alloc = [&](size_t bytes) -> void* {
        off = (off + 255) & ~(size_t)255;
        void* p = w + off;
        off += bytes;
        return p;
    };

    float* cst = (float*)alloc(4 * sizeof(float));
    double* psum = (double*)alloc((size_t)RBLOCKS * 3 * sizeof(double));
    float* pmin = (float*)alloc((size_t)RBLOCKS * 3 * sizeof(float));
    float* pmax = (float*)alloc((size_t)RBLOCKS * 3 * sizeof(float));
    float* tcs = (float*)alloc((size_t)F * 8 * sizeof(float));
    uint32_t* tz = (uint32_t*)alloc((size_t)F * sizeof(uint32_t));
    uint32_t* tbox = (uint32_t*)alloc((size_t)F * sizeof(uint32_t));
    u16* blockHist = (u16*)alloc((size_t)NB * NC * sizeof(u16));       // 8 MB
    uint32_t* cellOff = (uint32_t*)alloc(((size_t)NC + 1) * sizeof(uint32_t));
    uint32_t* blockSum = (uint32_t*)alloc(64 * sizeof(uint32_t));
    uint32_t* pairs = (uint32_t*)alloc((size_t)F * 16 * sizeof(uint32_t));
    size_t needed = off;  // ~19 MB for F=100k

    if (ws_size < needed) {
        // sentinel: encodes ws_size in MB (bf16-representable integers)
        float code = 20000.0f + (float)(ws_size >> 20);
        k_diag<<<(RESN * RESN * 3) / 256, 256, 0, stream>>>(out, code);
        return;
    }

    k_reduce1<<<RBLOCKS, 256, 0, stream>>>(u, nrows, psum, pmin, pmax);
    k_reduce2<<<1, 256, 0, stream>>>(psum, pmin, pmax, nrows, cst);
    k_setup<<<(F + 255) / 256, 256, 0, stream>>>(u, faces, mvps, light, cst, F,
                                                 tcs, tz, tbox);
    k_count<<<NB * NS, 256, 0, stream>>>(tbox, F, blockHist);
    k_scanA1<<<64, 1024, 0, stream>>>(blockHist, cellOff, blockSum);
    k_scanB<<<64, 1024, 0, stream>>>(cellOff, blockSum);
    k_place<<<NB * NS, 256, 0, stream>>>(tbox, blockHist, cellOff, pairs, F);
    k_cellsort<<<NC / CPB, 256, 0, stream>>>(cellOff, tz, pairs, F);
    k_raster<<<(RESN * RESN) / 256, 256, 0, stream>>>(tcs, cellOff, pairs, basec, bg, out, F);
}

// Round 11
// 153.446 us; speedup vs baseline: 1.0243x; 1.0243x over previous
//
#include <hip/hip_runtime.h>
#include <stdint.h>

// Match numpy f32 elementwise semantics: no implicit FMA contraction.
#pragma clang fp contract(off)

#define GRIDN 256
#define NC (GRIDN * GRIDN)
#define RESN 512
#define RBLOCKS 256
#define CAP 1024      // per-cell sort capacity; CAP=2048 regressed 80us (r7: tail-bound)
#define CPB 16        // cells per cellsort block
#define NB 64         // tri chunks
#define NS 16         // cell-space slices (4096 cells = 16 grid rows = 8KB LDS)
#define SBINS 2048    // packed u32 bins per slice

typedef unsigned short bfraw;
typedef unsigned short u16;

__device__ __forceinline__ float bf2f(bfraw h) {
    return __uint_as_float(((uint32_t)h) << 16);   // bf16 upcast is exact
}
__device__ __forceinline__ bfraw f2bf(float f) {
    uint32_t b = __float_as_uint(f);               // RNE f32 -> bf16
    return (bfraw)((b + 0x7FFFu + ((b >> 16) & 1u)) >> 16);
}
__device__ __forceinline__ uint32_t fkey(float f) {
    uint32_t b = __float_as_uint(f);
    return (b & 0x80000000u) ? ~b : (b | 0x80000000u);
}

// ---------------- partial reduce (sum fp64, min/max fp32) ----------------
__global__ __launch_bounds__(256) void k_reduce1(const bfraw* __restrict__ u, int nrows,
                                                 double* __restrict__ psum,
                                                 float* __restrict__ pmin,
                                                 float* __restrict__ pmax) {
    __shared__ double ssum[256 * 3];
    __shared__ float smin[256 * 3];
    __shared__ float smax[256 * 3];
    int t = threadIdx.x;
    double s0 = 0.0, s1 = 0.0, s2 = 0.0;
    float mn0 = INFINITY, mn1 = INFINITY, mn2 = INFINITY;
    float mx0 = -INFINITY, mx1 = -INFINITY, mx2 = -INFINITY;
    for (int r = blockIdx.x * 256 + t; r < nrows; r += 256 * RBLOCKS) {
        float a = bf2f(u[3 * r + 0]);
        float b = bf2f(u[3 * r + 1]);
        float c = bf2f(u[3 * r + 2]);
        s0 += (double)a; s1 += (double)b; s2 += (double)c;
        mn0 = fminf(mn0, a); mx0 = fmaxf(mx0, a);
        mn1 = fminf(mn1, b); mx1 = fmaxf(mx1, b);
        mn2 = fminf(mn2, c); mx2 = fmaxf(mx2, c);
    }
    ssum[t * 3 + 0] = s0; ssum[t * 3 + 1] = s1; ssum[t * 3 + 2] = s2;
    smin[t * 3 + 0] = mn0; smin[t * 3 + 1] = mn1; smin[t * 3 + 2] = mn2;
    smax[t * 3 + 0] = mx0; smax[t * 3 + 1] = mx1; smax[t * 3 + 2] = mx2;
    __syncthreads();
    for (int st = 128; st > 0; st >>= 1) {
        if (t < st) {
            for (int c = 0; c < 3; c++) {
                ssum[t * 3 + c] += ssum[(t + st) * 3 + c];
                smin[t * 3 + c] = fminf(smin[t * 3 + c], smin[(t + st) * 3 + c]);
                smax[t * 3 + c] = fmaxf(smax[t * 3 + c], smax[(t + st) * 3 + c]);
            }
        }
        __syncthreads();
    }
    if (t == 0) {
        for (int c = 0; c < 3; c++) {
            psum[blockIdx.x * 3 + c] = ssum[c];
            pmin[blockIdx.x * 3 + c] = smin[c];
            pmax[blockIdx.x * 3 + c] = smax[c];
        }
    }
}

// ---------------- finalize constants ----------------
__global__ __launch_bounds__(256) void k_reduce2(const double* __restrict__ psum,
                                                 const float* __restrict__ pmin,
                                                 const float* __restrict__ pmax,
                                                 int nrows, float* __restrict__ cst) {
    __shared__ double ssum[256 * 3];
    __shared__ float smin[256 * 3];
    __shared__ float smax[256 * 3];
    int t = threadIdx.x;
    for (int c = 0; c < 3; c++) {
        ssum[t * 3 + c] = psum[t * 3 + c];
        smin[t * 3 + c] = pmin[t * 3 + c];
        smax[t * 3 + c] = pmax[t * 3 + c];
    }
    __syncthreads();
    for (int st = 128; st > 0; st >>= 1) {
        if (t < st) {
            for (int c = 0; c < 3; c++) {
                ssum[t * 3 + c] += ssum[(t + st) * 3 + c];
                smin[t * 3 + c] = fminf(smin[t * 3 + c], smin[(t + st) * 3 + c]);
                smax[t * 3 + c] = fmaxf(smax[t * 3 + c], smax[(t + st) * 3 + c]);
            }
        }
        __syncthreads();
    }
    if (t == 0) {
        float fn = (float)nrows;
        float m0 = (float)ssum[0] / fn;
        float m1 = (float)ssum[1] / fn;
        float m2 = (float)ssum[2] / fn;
        // fp32 rounding is monotone: max_r(u - mean) == colmax - mean exactly.
        float vmax = fmaxf(fmaxf(smax[0] - m0, smax[1] - m1), smax[2] - m2);
        float vmin = fminf(fminf(smin[0] - m0, smin[1] - m1), smin[2] - m2);
        float span = fmaxf(vmax - vmin, 1e-06f);
        float s = 0.5f / span;   // SCALE / span
        cst[0] = m0; cst[1] = m1; cst[2] = m2; cst[3] = s;
    }
}

// ---------------- per-triangle setup (pure streaming, NO atomics) ----------------
// tcs layout per tri (8 floats): cpx0,cpy0,cpx1,cpy1,cpx2,cpy2,shade,0
// tbox: lox | loy<<8 | hx<<16 | hy<<24  with hx=min(hix,lox+3), hy=min(hiy,loy+3)
__global__ __launch_bounds__(256) void k_setup(const bfraw* __restrict__ u,
                                               const int* __restrict__ faces,
                                               const bfraw* __restrict__ mvp,
                                               const bfraw* __restrict__ light,
                                               const float* __restrict__ cst,
                                               int F,
                                               float* __restrict__ tcs,
                                               uint32_t* __restrict__ tz,
                                               uint32_t* __restrict__ tbox) {
    int f = blockIdx.x * 256 + threadIdx.x;
    if (f >= F) return;
    float m0 = cst[0], m1 = cst[1], m2 = cst[2], s = cst[3];
    float M[12];
    for (int i = 0; i < 12; i++) M[i] = bf2f(mvp[i]);

    float vx[3], vy[3], vz[3], cpx[3], cpy[3], zc[3];
    for (int j = 0; j < 3; j++) {
        int idx = faces[3 * f + j];
        float a = bf2f(u[3 * idx + 0]);
        float b = bf2f(u[3 * idx + 1]);
        float c = bf2f(u[3 * idx + 2]);
        float x = (a - m0) * s;
        float y = (b - m1) * s;
        float z = (c - m2) * s;
        vx[j] = x; vy[j] = y; vz[j] = z;
        // BLAS-style ascending-k fma chain; w=1 -> plain add of M[row][3]
        float cx = fmaf(x, M[0], 0.0f);
        cx = fmaf(y, M[1], cx); cx = fmaf(z, M[2], cx); cx = cx + M[3];
        float cy = fmaf(x, M[4], 0.0f);
        cy = fmaf(y, M[5], cy); cy = fmaf(z, M[6], cy); cy = cy + M[7];
        float cz = fmaf(x, M[8], 0.0f);
        cz = fmaf(y, M[9], cz); cz = fmaf(z, M[10], cz); cz = cz + M[11];
        cpx[j] = (cx + 1.0f) * 0.5f;
        cpy[j] = (cy + 1.0f) * 0.5f;
        zc[j] = cz;
    }
    float zmean = ((zc[0] + zc[1]) + zc[2]) / 3.0f;

    float e1x = vx[0] - vx[1], e1y = vy[0] - vy[1], e1z = vz[0] - vz[1];
    float e2x = vx[2] - vx[1], e2y = vy[2] - vy[1], e2z = vz[2] - vz[1];
    float nx = e1y * e2z - e1z * e2y;
    float ny = e1z * e2x - e1x * e2z;
    float nz = e1x * e2y - e1y * e2x;
    float nn = nx * nx;
    nn = nn + ny * ny;
    nn = nn + nz * nz;
    float d = sqrtf(nn) + 1e-10f;
    float inx = nx / d, iny = ny / d, inz = nz / d;

    float l0 = bf2f(light[0]), l1 = bf2f(light[1]), l2 = bf2f(light[2]);
    float p0 = (-l0) * inx;
    float p1 = (-l1) * iny;
    float p2 = (-l2) * inz;
    float shading = fmaxf((p0 + p1) + p2, 0.0f);

    tcs[f * 8 + 0] = cpx[0]; tcs[f * 8 + 1] = cpy[0];
    tcs[f * 8 + 2] = cpx[1]; tcs[f * 8 + 3] = cpy[1];
    tcs[f * 8 + 4] = cpx[2]; tcs[f * 8 + 5] = cpy[2];
    tcs[f * 8 + 6] = shading;
    tcs[f * 8 + 7] = 0.0f;

    tz[f] = fkey(zmean);

    float mnx = fminf(fminf(cpx[0], cpx[1]), cpx[2]);
    float mny = fminf(fminf(cpy[0], cpy[1]), cpy[2]);
    float mxx = fmaxf(fmaxf(cpx[0], cpx[1]), cpx[2]);
    float mxy = fmaxf(fmaxf(cpy[0], cpy[1]), cpy[2]);
    int lox = (int)floorf(mnx * 256.0f); lox = lox < 0 ? 0 : (lox > 255 ? 255 : lox);
    int loy = (int)floorf(mny * 256.0f); loy = loy < 0 ? 0 : (loy > 255 ? 255 : loy);
    int hix = (int)floorf(mxx * 256.0f); hix = hix < 0 ? 0 : (hix > 255 ? 255 : hix);
    int hiy = (int)floorf(mxy * 256.0f); hiy = hiy < 0 ? 0 : (hiy > 255 ? 255 : hiy);
    int hx = hix < lox + 3 ? hix : lox + 3;   // SPAN=4 window
    int hy = hiy < loy + 3 ? hiy : loy + 3;
    tbox[f] = (uint32_t)lox | ((uint32_t)loy << 8) | ((uint32_t)hx << 16) | ((uint32_t)hy << 24);
}

// ---------------- slice-parallel LDS histogram ----------------
// Slice sl owns grid rows [16*sl, 16*sl+16) (cell>>12 == yy>>4 exactly), so the
// y-loop is clamped instead of per-cell filtered.
__global__ __launch_bounds__(256) void k_count(const uint32_t* __restrict__ tbox,
                                               int F,
                                               u16* __restrict__ blockHist) {
    __shared__ uint32_t hist[SBINS];
    int b = blockIdx.x >> 4;          // chunk
    int sl = blockIdx.x & (NS - 1);   // slice
    int chunk = (F + NB - 1) / NB;
    int fs = b * chunk;
    int fe = fs + chunk < F ? fs + chunk : F;
    int y0 = sl * 16, y1 = y0 + 15;
    for (int i = threadIdx.x; i < SBINS; i += 256) hist[i] = 0u;
    __syncthreads();
    for (int f = fs + threadIdx.x; f < fe; f += 256) {
        uint32_t bx = tbox[f];
        int lox = bx & 255, loy = (bx >> 8) & 255;
        int hx = (bx >> 16) & 255, hy = bx >> 24;
        int ys = loy > y0 ? loy : y0;
        int ye = hy < y1 ? hy : y1;
        for (int yy = ys; yy <= ye; yy++) {
            for (int xx = lox; xx <= hx; xx++) {
                uint32_t c = (uint32_t)(yy * GRIDN + xx) & 4095u;
                atomicAdd(&hist[c >> 1], 1u << (16u * (c & 1u)));
            }
        }
    }
    __syncthreads();
    uint32_t* dst = (uint32_t*)(blockHist + (size_t)b * NC) + sl * SBINS;
    for (int i = threadIdx.x; i < SBINS; i += 256) dst[i] = hist[i];
}

// ---------------- fused: per-cell block-prefix + block-local scan ----------------
__global__ __launch_bounds__(1024) void k_scanA1(u16* __restrict__ blockHist,
                                                 uint32_t* __restrict__ cellOff,
                                                 uint32_t* __restrict__ blockSum) {
    __shared__ uint32_t sc[1024];
    int B = blockIdx.x, t = threadIdx.x;
    int c = B * 1024 + t;
    uint32_t tot = 0;
    for (int b = 0; b < NB; b++) {
        size_t o = (size_t)b * NC + c;
        uint32_t v = blockHist[o];
        blockHist[o] = (u16)tot;              // per-(chunk,cell) base
        tot += v;
    }
    sc[t] = tot;
    __syncthreads();
    for (int st = 1; st < 1024; st <<= 1) {
        uint32_t a = 0;
        if (t >= st) a = sc[t - st];
        __syncthreads();
        if (t >= st) sc[t] += a;
        __syncthreads();
    }
    cellOff[c] = sc[t] - tot;   // exclusive within block
    if (t == 1023) blockSum[B] = sc[1023];
}

// ---------------- fused: block-base add (each block prefixes the 64 sums) -------
__global__ __launch_bounds__(1024) void k_scanB(uint32_t* __restrict__ cellOff,
                                                const uint32_t* __restrict__ blockSum) {
    __shared__ uint32_t pre[65];
    int B = blockIdx.x, t = threadIdx.x;
    if (t == 0) {
        uint32_t run = 0;
        for (int i = 0; i < 64; i++) { pre[i] = run; run += blockSum[i]; }
        pre[64] = run;   // grand total
    }
    __syncthreads();
    cellOff[B * 1024 + t] += pre[B];
    if (B == 63 && t == 1023) cellOff[NC] = pre[64];
}

// ---------------- slice-parallel place: LDS cursor = rank within (chunk,cell) -----
__global__ __launch_bounds__(256) void k_place(const uint32_t* __restrict__ tbox,
                                               const u16* __restrict__ blockHist,
                                               const uint32_t* __restrict__ cellOff,
                                               uint32_t* __restrict__ pairs,
                                               int F) {
    __shared__ uint32_t hist[SBINS];
    int b = blockIdx.x >> 4;
    int sl = blockIdx.x & (NS - 1);
    int chunk = (F + NB - 1) / NB;
    int fs = b * chunk;
    int fe = fs + chunk < F ? fs + chunk : F;
    int y0 = sl * 16, y1 = y0 + 15;
    uint32_t pcap = (uint32_t)F * 16u;
    for (int i = threadIdx.x; i < SBINS; i += 256) hist[i] = 0u;
    __syncthreads();
    for (int f = fs + threadIdx.x; f < fe; f += 256) {
        uint32_t bx = tbox[f];
        int lox = bx & 255, loy = (bx >> 8) & 255;
        int hx = (bx >> 16) & 255, hy = bx >> 24;
        int ys = loy > y0 ? loy : y0;
        int ye = hy < y1 ? hy : y1;
        for (int yy = ys; yy <= ye; yy++) {
            for (int xx = lox; xx <= hx; xx++) {
                uint32_t cell = (uint32_t)(yy * GRIDN + xx);
                uint32_t c = cell & 4095u;
                uint32_t sh = 16u * (c & 1u);
                uint32_t old = atomicAdd(&hist[c >> 1], 1u << sh);
                uint32_t r = (old >> sh) & 0xFFFFu;
                uint32_t pos = cellOff[cell] + (uint32_t)blockHist[(size_t)b * NC + cell] + r;
                if (pos < pcap) pairs[pos] = (uint32_t)f;   // defensive vs poisoned replay
            }
        }
    }
}

// ---------------- top-64 selection for cells with n>64 ONLY ----------------
// r3-verified design: cells with n<=64 need NO ordering — the raster argmins
// the (zkey,id) key among inside hits, which equals the reference's
// sorted-first-hit. Only KMAX-truncated cells need the 64-smallest selection.
// This deletes ~60% of cellsort's work instead of redistributing it
// (r8/r9/r10 all showed redistribution is neutral — tail-dominated).
__global__ __launch_bounds__(256) void k_cellsort(const uint32_t* __restrict__ cellOff,
                                                  const uint32_t* __restrict__ tz,
                                                  uint32_t* __restrict__ pairs,
                                                  int F) {
    __shared__ uint64_t lkeys[CAP];
    uint32_t pcap = (uint32_t)F * 16u;
    int t = threadIdx.x;
    int cell0 = blockIdx.x * CPB;
    for (int ci = 0; ci < CPB; ci++) {
        int cell = cell0 + ci;
        uint32_t off = cellOff[cell];       // block-uniform -> s_load
        uint32_t end = cellOff[cell + 1];
        if (off > pcap || end > pcap || end < off) continue;   // defensive (uniform)
        uint32_t n = end - off;
        if (n <= 64u) continue;             // uniform: no truncation -> no sort needed
        uint32_t m = n > CAP ? CAP : n;
        for (uint32_t i = t; i < m; i += 256) {
            uint32_t id = pairs[off + i];
            if (id >= (uint32_t)F) id = 0;   // defensive
            lkeys[i] = ((uint64_t)tz[id] << 32) | id;
        }
        __syncthreads();
        uint64_t k0 = ~0ull, k1 = ~0ull, k2 = ~0ull, k3 = ~0ull;
        uint32_t i0 = t, i1 = t + 256, i2 = t + 512, i3 = t + 768;
        if (i0 < m) k0 = lkeys[i0];
        if (i1 < m) k1 = lkeys[i1];
        if (i2 < m) k2 = lkeys[i2];
        if (i3 < m) k3 = lkeys[i3];
        uint32_t r0 = 0, r1 = 0, r2 = 0, r3 = 0;
        for (uint32_t j = 0; j < m; j++) {
            uint64_t kj = lkeys[j];   // broadcast (all lanes same addr: conflict-free)
            r0 += (kj < k0) ? 1u : 0u;
            r1 += (kj < k1) ? 1u : 0u;
            r2 += (kj < k2) ? 1u : 0u;
            r3 += (kj < k3) ? 1u : 0u;
        }
        if (i0 < m && r0 < 64u) pairs[off + r0] = (uint32_t)(k0 & 0xFFFFFFFFu);
        if (i1 < m && r1 < 64u) pairs[off + r1] = (uint32_t)(k1 & 0xFFFFFFFFu);
        if (i2 < m && r2 < 64u) pairs[off + r2] = (uint32_t)(k2 & 0xFFFFFFFFu);
        if (i3 < m && r3 < 64u) pairs[off + r3] = (uint32_t)(k3 & 0xFFFFFFFFu);
        __syncthreads();   // protect lkeys before next cell's staging (uniform)
    }
}

// ---------------- raster: argmin (zkey,id) over inside hits of min(n,64) --------
// For n<=64 the list is the full (unsorted) candidate set; for n>64 cellsort
// left the 64 smallest keys in the first 64 slots (any order). Min key among
// inside hits == reference's first-hit-in-sorted-order. tz gathered only on
// inside hits (few per pixel; tz is L2-resident).
__global__ __launch_bounds__(256) void k_raster(const float* __restrict__ tcs,
                                                const uint32_t* __restrict__ tz,
                                                const uint32_t* __restrict__ cellOff,
                                                const uint32_t* __restrict__ pairs,
                                                const bfraw* __restrict__ basec,
                                                const bfraw* __restrict__ bg,
                                                bfraw* __restrict__ out, int F) {
    int p = blockIdx.x * 256 + threadIdx.x;
    int col = p & (RESN - 1);
    int row = p >> 9;
    float px = ((float)col + 0.5f) / 512.0f;
    float py = ((float)row + 0.5f) / 512.0f;
    int cell = (row >> 1) * GRIDN + (col >> 1);
    uint32_t pcap = (uint32_t)F * 16u;
    uint32_t off = cellOff[cell];
    uint32_t end = cellOff[cell + 1];
    uint32_t m = 0;
    if (off <= pcap && end <= pcap && end >= off) {
        uint32_t n = end - off;
        m = n > 64u ? 64u : n;
    }
    uint64_t best = ~0ull;
    float bestSh = 0.0f;
    for (uint32_t k = 0; k < m; k++) {
        uint32_t id = pairs[off + k];
        if (id >= (uint32_t)F) continue;   // defensive
        const float4 A = *(const float4*)(tcs + (size_t)id * 8);
        const float4 B = *(const float4*)(tcs + (size_t)id * 8 + 4);
        float ax = A.x, ay = A.y, bx = A.z, by = A.w, cx = B.x, cy = B.y;
        float e0 = (bx - ax) * (py - ay) - (by - ay) * (px - ax);
        float e1 = (cx - bx) * (py - by) - (cy - by) * (px - bx);
        float e2 = (ax - cx) * (py - cy) - (ay - cy) * (px - cx);
        bool inside = (e0 >= 0.0f && e1 >= 0.0f && e2 >= 0.0f) ||
                      (e0 <= 0.0f && e1 <= 0.0f && e2 <= 0.0f);
        if (inside) {
            uint64_t key = ((uint64_t)tz[id] << 32) | id;
            if (key < best) { best = key; bestSh = B.z; }
        }
    }
    float r, g, b;
    if (best != ~0ull) {
        uint32_t id = (uint32_t)(best & 0xFFFFFFFFu);
        r = bf2f(basec[3 * id + 0]) * bestSh;
        g = bf2f(basec[3 * id + 1]) * bestSh;
        b = bf2f(basec[3 * id + 2]) * bestSh;
    } else {
        r = bf2f(bg[0]); g = bf2f(bg[1]); b = bf2f(bg[2]);
    }
    int o = p * 3;
    out[o + 0] = f2bf(r);
    out[o + 1] = f2bf(g);
    out[o + 2] = f2bf(b);
}

// ---------------- diagnostic: ws too small -> encode ws MB into the image ----------------
__global__ __launch_bounds__(256) void k_diag(bfraw* __restrict__ out, float code) {
    out[blockIdx.x * 256 + threadIdx.x] = f2bf(code);
}

extern "C" void kernel_launch(void* const* d_in, const int* in_sizes, int n_in,
                              void* d_out, int out_size, void* d_ws, size_t ws_size,
                              hipStream_t stream) {
    const bfraw* u = (const bfraw*)d_in[0];
    const bfraw* mvps = (const bfraw*)d_in[1];
    const bfraw* light = (const bfraw*)d_in[2];
    const bfraw* bg = (const bfraw*)d_in[3];
    const bfraw* basec = (const bfraw*)d_in[4];
    const int* faces = (const int*)d_in[5];
    int nrows = in_sizes[0] / 3;
    int F = in_sizes[5] / 3;
    bfraw* out = (bfraw*)d_out;

    char* w = (char*)d_ws;
    size_t off = 0;
    auto alloc = [&](size_t bytes) -> void* {
        off = (off + 255) & ~(size_t)255;
        void* p = w + off;
        off += bytes;
        return p;
    };

    float* cst = (float*)alloc(4 * sizeof(float));
    double* psum = (double*)alloc((size_t)RBLOCKS * 3 * sizeof(double));
    float* pmin = (float*)alloc((size_t)RBLOCKS * 3 * sizeof(float));
    float* pmax = (float*)alloc((size_t)RBLOCKS * 3 * sizeof(float));
    float* tcs = (float*)alloc((size_t)F * 8 * sizeof(float));
    uint32_t* tz = (uint32_t*)alloc((size_t)F * sizeof(uint32_t));
    uint32_t* tbox = (uint32_t*)alloc((size_t)F * sizeof(uint32_t));
    u16* blockHist = (u16*)alloc((size_t)NB * NC * sizeof(u16));       // 8 MB
    uint32_t* cellOff = (uint32_t*)alloc(((size_t)NC + 1) * sizeof(uint32_t));
    uint32_t* blockSum = (uint32_t*)alloc(64 * sizeof(uint32_t));
    uint32_t* pairs = (uint32_t*)alloc((size_t)F * 16 * sizeof(uint32_t));
    size_t needed = off;  // ~19 MB for F=100k

    if (ws_size < needed) {
        // sentinel: encodes ws_size in MB (bf16-representable integers)
        float code = 20000.0f + (float)(ws_size >> 20);
        k_diag<<<(RESN * RESN * 3) / 256, 256, 0, stream>>>(out, code);
        return;
    }

    k_reduce1<<<RBLOCKS, 256, 0, stream>>>(u, nrows, psum, pmin, pmax);
    k_reduce2<<<1, 256, 0, stream>>>(psum, pmin, pmax, nrows, cst);
    k_setup<<<(F + 255) / 256, 256, 0, stream>>>(u, faces, mvps, light, cst, F,
                                                 tcs, tz, tbox);
    k_count<<<NB * NS, 256, 0, stream>>>(tbox, F, blockHist);
    k_scanA1<<<64, 1024, 0, stream>>>(blockHist, cellOff, blockSum);
    k_scanB<<<64, 1024, 0, stream>>>(cellOff, blockSum);
    k_place<<<NB * NS, 256, 0, stream>>>(tbox, blockHist, cellOff, pairs, F);
    k_cellsort<<<NC / CPB, 256, 0, stream>>>(cellOff, tz, pairs, F);
    k_raster<<<(RESN * RESN) / 256, 256, 0, stream>>>(tcs, tz, cellOff, pairs,
                                                      basec, bg, out, F);
}